// Round 1
// 92.078 us; speedup vs baseline: 1.0941x; 1.0941x over previous
//
#include <hip/hip_runtime.h>

// MixtureRouting: y[b,d,m] = sum_p x[b,d,p] * coef[b,p,m]
//   lh[b,p,m]  = pi[b,m] * prod_i( sig[b,i,m] / (PI*((mu[b,i,p]-mu[b,i,m])^2 + sig[b,i,m]^2)) )
//   coef[p,m]  = lh[p,m] / rowsum[p]
// R7 -> R8: total was ~100.7us = ~82us harness ws-poison fills + ~18us of our kernels.
// Attack the 18us:
//   (a) gemm was L2-bound: each 16-col block re-read all of xbf[b] (384KB x 128 blocks/b
//       = 196 MB L2 ~ 5.7us). Now 32 m-cols/block: A-frags feed TWO 16-col MFMA tiles ->
//       98 MB L2. grid 64xB = 256 blocks = 1/CU.
//   (b) invrow folded into the register-built B-fragment (B = bf16(lh*invrow)) instead of
//       pre-scaling A. xbf becomes a pure f32->bf16 pad/convert with NO rowsum dependency,
//       so it is fused into the rowsum kernel (768 elems/block flat) -> 2 launches, not 3.
//   (c) invs[p] = rcp(sum of 8 rowsum partials) staged in LDS alongside mus at gemm start.

typedef float v4f __attribute__((ext_vector_type(4)));
typedef float f32x4 __attribute__((ext_vector_type(4)));
typedef short bf16x8 __attribute__((ext_vector_type(8)));

namespace {
constexpr int BB = 4;
constexpr int DD = 81;
constexpr int KK = 2048;
constexpr int MROWS = 96;                 // padded d-rows for MFMA (6 tiles of 16)
constexpr float INV_PI4 = 1.0f / 97.40909103400243f;

// ws layout (bytes) -- only 1.8 MB used
constexpr size_t OFF_XBF = 0;                                     // ushort[B][96][K]
constexpr size_t OFF_RSP = (size_t)BB * MROWS * KK * 2;           // float[B][8][K]
}

__device__ __forceinline__ unsigned short f2bf(float f) {
    union { float f; unsigned int u; } v; v.f = f;
    unsigned int u = v.u;
    unsigned int r = (u + 0x7FFFu + ((u >> 16) & 1u)) >> 16;   // RNE
    return (unsigned short)r;
}

// ---------------------------------------------------------------------------
// prep: grid = B * 32 p-chunks * 8 m-slices = 1024 blocks, 256 threads.
// Part 1 (rowsum): rowsumPart[b][ms][p0+lane] = sum over 256 m of lh[p,m].
// Part 2 (xbf, fused): pure pad/convert x -> bf16; 768 flat elems per block
//   (1024 blocks * 768 = 4*96*2048 exactly; same b as the rowsum slice).
// ---------------------------------------------------------------------------
__global__ __launch_bounds__(256) void prep_kernel(const float* __restrict__ x,
                                                   const float* __restrict__ pi_,
                                                   const float* __restrict__ mu,
                                                   const float* __restrict__ sig,
                                                   float* __restrict__ rowsumPart,
                                                   unsigned short* __restrict__ xbf) {
    __shared__ v4f   mush[256];
    __shared__ v4f   s2sh[256];
    __shared__ float csh[256];
    __shared__ float red[4][64];

    int blk = blockIdx.x;
    int b   = blk >> 8;
    int pc  = (blk & 255) >> 3;          // 0..31
    int ms  = blk & 7;                   // 0..7
    int p0  = pc * 64;
    int m0  = ms * 256;
    int t   = threadIdx.x;
    int lane = t & 63, w = t >> 6;

    const float* mub = mu  + (size_t)b * 4 * KK;
    const float* sgb = sig + (size_t)b * 4 * KK;
    const float* pib = pi_ + (size_t)b * KK;

    // stage m-side constants (thread t -> m0+t)
    {
        int m = m0 + t;
        v4f mm = {mub[m], mub[KK + m], mub[2 * KK + m], mub[3 * KK + m]};
        v4f sg = {sgb[m], sgb[KK + m], sgb[2 * KK + m], sgb[3 * KK + m]};
        mush[t] = mm;
        s2sh[t] = sg * sg;
        csh[t]  = pib[m] * ((sg.x * sg.y) * (sg.z * sg.w)) * INV_PI4;
    }
    // per-lane p-side constants
    int p = p0 + lane;
    v4f mp = {mub[p], mub[KK + p], mub[2 * KK + p], mub[3 * KK + p]};

    // fused xbf convert (independent of LDS staging; overlaps the barrier wait).
    // flat elem e = blk*768 + t + k*256; within b: rem = (blk&255)*768 + ...
    {
        int rembase = (blk & 255) * 768;
        const float* xb = x + (size_t)b * DD * KK;
#pragma unroll
        for (int k = 0; k < 3; ++k) {
            int rem = rembase + k * 256 + t;
            int d   = rem >> 11;           // /2048
            int pp  = rem & 2047;
            float v = 0.f;
            if (d < DD) v = xb[(size_t)d * KK + pp];
            xbf[(size_t)b * MROWS * KK + rem] = f2bf(v);
        }
    }
    __syncthreads();

    float sum = 0.f;
#pragma unroll 4
    for (int i = 0; i < 64; ++i) {
        int mi = w * 64 + i;                       // local m (this wave's quarter)
        v4f d = mp - mush[mi];
        v4f q = d * d + s2sh[mi];
        float den = (q.x * q.y) * (q.z * q.w);
        sum += csh[mi] * __builtin_amdgcn_rcpf(den);
    }

    red[w][lane] = sum;
    __syncthreads();
    if (t < 64)
        rowsumPart[((size_t)(b * 8 + ms)) * KK + p0 + t] =
            red[0][t] + red[1][t] + red[2][t] + red[3][t];
}

// ---------------------------------------------------------------------------
// gemm (fused coef): grid (64, B), 512 threads = 8 waves. Block = (b, 32-col m-tile),
// full K=2048; wave w owns p-slice [w*256, w*256+256).
// Per ks-step: lane (r,q) COMPUTES B-fragments coef[p=pb..pb+7][m] in registers for
// TWO 16-col tiles (m = m0+r and m0+16+r), sharing the mus/invs LDS reads and the
// 6 A-frag loads (xbf, L2-resident) -> 12x v_mfma_f32_16x16x32_bf16.
// A[m=lane&15][k=quad*8+j]; B[n=lane&15][k=quad*8+j]; D col=lane&15,row=quad*4+reg.
// LDS: 32KB mus + 8KB invs during K-loop; reused post-barrier as 48KB reduce buffer.
// Epilogue: two passes (one per 16-col tile) over the cross-wave reduce buffer.
// ---------------------------------------------------------------------------
__global__ __launch_bounds__(512) void gemm_kernel(const float* __restrict__ pi_,
                                                   const float* __restrict__ mu,
                                                   const float* __restrict__ sig,
                                                   const float* __restrict__ rowsumPart,
                                                   const unsigned short* __restrict__ xbf,
                                                   float* __restrict__ out) {
    __shared__ __align__(16) char smem[49152];          // 48 KB
    v4f*   mus  = (v4f*)smem;                           // [2048] (32 KB)
    float* invs = (float*)(smem + 32768);               // [2048] (8 KB)
    f32x4 (*red)[6][64] = (f32x4 (*)[6][64])smem;       // [8][6][64] after barrier (48 KB)

    int t = threadIdx.x;
    int w = t >> 6, lane = t & 63;
    int r = lane & 15, q = lane >> 4;
    int b  = blockIdx.y;
    int m0 = blockIdx.x * 32;

    const float* mub = mu  + (size_t)b * 4 * KK;
    const float* sgb = sig + (size_t)b * 4 * KK;
    const float* rspb = rowsumPart + (size_t)b * 8 * KK;

    // stage mu[b] transposed: mus[p] = {mu0[p], mu1[p], mu2[p], mu3[p]}
    for (int i = t; i < KK; i += 512)
        mus[i] = (v4f){mub[i], mub[KK + i], mub[2 * KK + i], mub[3 * KK + i]};
    // stage invrow[p] = 1 / sum_s rowsumPart[s][p]
    for (int i = t; i < KK; i += 512) {
        float s = 0.f;
#pragma unroll
        for (int sidx = 0; sidx < 8; ++sidx) s += rspb[(size_t)sidx * KK + i];
        invs[i] = __builtin_amdgcn_rcpf(s);
    }

    // per-lane m-side constants for the two 16-col tiles
    int mA = m0 + r, mB = m0 + 16 + r;
    v4f mmA = {mub[mA], mub[KK + mA], mub[2 * KK + mA], mub[3 * KK + mA]};
    v4f sgA = {sgb[mA], sgb[KK + mA], sgb[2 * KK + mA], sgb[3 * KK + mA]};
    v4f s2A = sgA * sgA;
    float cA = pi_[(size_t)b * KK + mA] * ((sgA.x * sgA.y) * (sgA.z * sgA.w)) * INV_PI4;
    v4f mmB = {mub[mB], mub[KK + mB], mub[2 * KK + mB], mub[3 * KK + mB]};
    v4f sgB = {sgb[mB], sgb[KK + mB], sgb[2 * KK + mB], sgb[3 * KK + mB]};
    v4f s2B = sgB * sgB;
    float cB = pi_[(size_t)b * KK + mB] * ((sgB.x * sgB.y) * (sgB.z * sgB.w)) * INV_PI4;

    const unsigned short* Abase = xbf + ((size_t)(b * MROWS + r)) * KK;

    f32x4 acc0[6], acc1[6];
#pragma unroll
    for (int i = 0; i < 6; ++i) { acc0[i] = (f32x4)0.f; acc1[i] = (f32x4)0.f; }

    __syncthreads();

    int pw = w * 256;
#pragma unroll
    for (int ks = 0; ks < 8; ++ks) {
        int pb = pw + ks * 32 + q * 8;
        // build B fragments in registers: Bf*[j] = bf16(coef[pb+j][m*])
        bf16x8 Bf0, Bf1;
#pragma unroll
        for (int j = 0; j < 8; ++j) {
            v4f mp  = mus[pb + j];
            float iv = invs[pb + j];
            v4f d0 = mp - mmA;
            v4f q0 = d0 * d0 + s2A;
            float den0 = (q0.x * q0.y) * (q0.z * q0.w);
            Bf0[j] = (short)f2bf((cA * iv) * __builtin_amdgcn_rcpf(den0));
            v4f d1 = mp - mmB;
            v4f q1 = d1 * d1 + s2B;
            float den1 = (q1.x * q1.y) * (q1.z * q1.w);
            Bf1[j] = (short)f2bf((cB * iv) * __builtin_amdgcn_rcpf(den1));
        }
        bf16x8 Af[6];
#pragma unroll
        for (int Mt = 0; Mt < 6; ++Mt)
            Af[Mt] = *(const bf16x8*)(Abase + (size_t)Mt * 16 * KK + pb);
#pragma unroll
        for (int Mt = 0; Mt < 6; ++Mt) {
            acc0[Mt] = __builtin_amdgcn_mfma_f32_16x16x32_bf16(Af[Mt], Bf0, acc0[Mt], 0, 0, 0);
            acc1[Mt] = __builtin_amdgcn_mfma_f32_16x16x32_bf16(Af[Mt], Bf1, acc1[Mt], 0, 0, 0);
        }
    }

    // epilogue: two passes over the 48KB cross-wave reduce buffer (reuses mus/invs)
    int col = t & 15;
    int dr  = t >> 4;                    // 0..31
#pragma unroll
    for (int nt = 0; nt < 2; ++nt) {
        __syncthreads();                 // nt=0: waves done reading mus/invs
                                         // nt=1: waves done reading red pass 0
#pragma unroll
        for (int Mt = 0; Mt < 6; ++Mt)
            red[w][Mt][lane] = (nt == 0) ? acc0[Mt] : acc1[Mt];
        __syncthreads();
        // 1536 outputs (96 rows x 16 cols), 512 threads -> 3 each; skip d >= 81.
#pragma unroll
        for (int k = 0; k < 3; ++k) {
            int d = dr + 32 * k;         // 0..95
            if (d < DD) {
                int Mt  = d >> 4;
                int row = d & 15;
                int l   = (row >> 2) * 16 + col;
                int j   = row & 3;
                float s = 0.f;
#pragma unroll
                for (int ww = 0; ww < 8; ++ww) s += red[ww][Mt][l][j];
                out[((size_t)(b * DD + d)) * KK + m0 + nt * 16 + col] = s;
            }
        }
    }
}

extern "C" void kernel_launch(void* const* d_in, const int* in_sizes, int n_in,
                              void* d_out, int out_size, void* d_ws, size_t ws_size,
                              hipStream_t stream) {
    const float* x   = (const float*)d_in[0];
    const float* pi_ = (const float*)d_in[1];
    const float* mu  = (const float*)d_in[2];
    const float* sig = (const float*)d_in[3];
    float* out = (float*)d_out;

    unsigned short* xbf = (unsigned short*)((char*)d_ws + OFF_XBF);
    float* rowsumPart   = (float*)((char*)d_ws + OFF_RSP);

    prep_kernel<<<1024, 256, 0, stream>>>(x, pi_, mu, sig, rowsumPart, xbf);
    dim3 gg(KK / 32, BB);
    gemm_kernel<<<gg, 512, 0, stream>>>(pi_, mu, sig, rowsumPart, xbf, out);
}